// Round 9
// baseline (372.592 us; speedup 1.0000x reference)
//
#include <hip/hip_runtime.h>

#define HW1 50176   // 224*224
#define HW2 12544   // 112*112

typedef short bf16x8 __attribute__((ext_vector_type(8)));
typedef short bf16x4 __attribute__((ext_vector_type(4)));
typedef float f32x4  __attribute__((ext_vector_type(4)));

static __device__ __forceinline__ unsigned short f2bf(float f) {
  union { float f; unsigned int u; } v; v.f = f;
  unsigned int u = v.u;
  return (unsigned short)((u + 0x7fffu + ((u >> 16) & 1u)) >> 16);
}
static __device__ __forceinline__ float bf2f(unsigned short h) {
  union { unsigned int u; float f; } v; v.u = ((unsigned int)h) << 16;
  return v.f;
}

// ---------------- fused prep: 3 weight converts ------------------------------
__global__ __launch_bounds__(256) void prep_kernel(
    const float* __restrict__ conv4_w, const float* __restrict__ conv2_w,
    const float* __restrict__ off_w,
    unsigned short* __restrict__ wbf, unsigned short* __restrict__ wb2h,
    unsigned short* __restrict__ wb2l, unsigned short* __restrict__ wboh,
    unsigned short* __restrict__ wbol)
{
  int t = blockIdx.x * 256 + threadIdx.x;
  if (t < 147456) {                       // deform: [o][kk*128+c]
    int o = t / 1152, r = t % 1152;
    int kk = r / 128, c = r % 128;
    wbf[t] = f2bf(conv4_w[((size_t)o * 128 + c) * 9 + kk]);
  }
  int t2 = t - 147456;
  if (t2 >= 0 && t2 < 73728) {            // conv2 split: [o][kk*64+c]
    int o = t2 / 576, r = t2 % 576;
    int kk = r / 64, c = r % 64;
    float v = conv2_w[((size_t)o * 64 + c) * 9 + kk];
    unsigned short h = f2bf(v);
    wb2h[t2] = h; wb2l[t2] = f2bf(v - bf2f(h));
  }
  int t3 = t - (147456 + 73728);
  if (t3 >= 0 && t3 < 36864) {            // off conv split, padded to 32 rows
    int o = t3 / 1152, r = t3 % 1152;
    int kk = r / 128, c = r % 128;
    float v = (o < 18) ? off_w[((size_t)o * 128 + c) * 9 + kk] : 0.f;
    unsigned short h = f2bf(v);
    wboh[t3] = h; wbol[t3] = f2bf(v - bf2f(h));
  }
}

// ---------------- conv1: 3->64, 224x224, pad=1, +bias, relu, LDS-tiled ------
__global__ __launch_bounds__(256) void conv1_tiled_kernel(
    const float* __restrict__ x, const float* __restrict__ w,
    const float* __restrict__ bias, float* __restrict__ out)
{
  __shared__ float in_s[3][18][18];
  int tid = threadIdx.x;
  int tx = tid & 15, ty = tid >> 4;
  int tx0 = (blockIdx.x % 14) * 16, ty0 = (blockIdx.x / 14) * 16;
  int b = blockIdx.y;

  for (int t = tid; t < 972; t += 256) {
    int c = t / 324, r2 = t % 324;
    int r = r2 / 18, col = r2 % 18;
    int yy = ty0 + r - 1, xx = tx0 + col - 1;
    float v = 0.f;
    if (yy >= 0 && yy < 224 && xx >= 0 && xx < 224)
      v = x[((size_t)(b * 3 + c) * 224 + yy) * 224 + xx];
    in_s[c][r][col] = v;
  }
  __syncthreads();

  float xv[27];
  #pragma unroll
  for (int c = 0; c < 3; ++c)
    #pragma unroll
    for (int ky = 0; ky < 3; ++ky)
      #pragma unroll
      for (int kx = 0; kx < 3; ++kx)
        xv[c * 9 + ky * 3 + kx] = in_s[c][ty + ky][tx + kx];

  int oy = ty0 + ty, ox = tx0 + tx;
  size_t obase = ((size_t)b * 64) * HW1 + (size_t)oy * 224 + ox;
  for (int o0 = 0; o0 < 64; o0 += 16) {
    float acc[16];
    #pragma unroll
    for (int oi = 0; oi < 16; ++oi) acc[oi] = bias[o0 + oi];
    #pragma unroll
    for (int oi = 0; oi < 16; ++oi) {
      const float* wp = w + (size_t)(o0 + oi) * 27;
      #pragma unroll
      for (int k = 0; k < 27; ++k)
        acc[oi] += xv[k] * wp[k];
    }
    #pragma unroll
    for (int oi = 0; oi < 16; ++oi)
      out[obase + (size_t)(o0 + oi) * HW1] = fmaxf(acc[oi], 0.f);
  }
}

// ---------------- BN stats: per-block partials (DETERMINISTIC) ---------------
__global__ __launch_bounds__(256) void bn_stats_part_kernel(
    const float* __restrict__ in, float* __restrict__ part, int C, int HW)
{
  int c = blockIdx.y;
  int NB = gridDim.x;
  float s = 0.f, s2 = 0.f;
  int stride = NB * 256;
  int start = blockIdx.x * 256 + threadIdx.x;
  for (int b = 0; b < 4; ++b) {
    const float* p = in + (size_t)(b * C + c) * HW;
    for (int i = start; i < HW; i += stride) {
      float v = p[i];
      s += v; s2 += v * v;
    }
  }
  #pragma unroll
  for (int off = 32; off > 0; off >>= 1) {
    s  += __shfl_down(s, off, 64);
    s2 += __shfl_down(s2, off, 64);
  }
  __shared__ float red[8];
  int wid = threadIdx.x >> 6, lane = threadIdx.x & 63;
  if (lane == 0) { red[wid * 2] = s; red[wid * 2 + 1] = s2; }
  __syncthreads();
  if (threadIdx.x == 0) {
    float ts = 0.f, ts2 = 0.f;
    for (int i = 0; i < 4; ++i) { ts += red[i * 2]; ts2 += red[i * 2 + 1]; }
    part[((size_t)c * NB + blockIdx.x) * 2]     = ts;
    part[((size_t)c * NB + blockIdx.x) * 2 + 1] = ts2;
  }
}

// ---------------- BN finalize: fixed-order partial reduce -> scale/shift -----
__global__ void bn_finalize_kernel(const float* __restrict__ part, int NB,
                                   const float* __restrict__ g,
                                   const float* __restrict__ bb,
                                   float inv_n, float* __restrict__ ss, int C)
{
  int c = threadIdx.x;
  if (c < C) {
    float s = 0.f, s2 = 0.f;
    for (int i = 0; i < NB; ++i) {
      s  += part[((size_t)c * NB + i) * 2];
      s2 += part[((size_t)c * NB + i) * 2 + 1];
    }
    float m = s * inv_n;
    float v = s2 * inv_n - m * m;
    float sc = rsqrtf(v + 1e-5f) * g[c];
    ss[2 * c] = sc;
    ss[2 * c + 1] = bb[c] - m * sc;
  }
}

// ---------------- BN1 apply + 2x2 avgpool, NCHW -> NHWC (64 ch) -------------
__global__ __launch_bounds__(256) void bn1_pool_nhwc_kernel(
    const float* __restrict__ h1, const float* __restrict__ ss,
    float* __restrict__ out)
{
  __shared__ float tile[16][65];
  int b = blockIdx.z, y = blockIdx.y, x0 = blockIdx.x * 16;
  int tid = threadIdx.x;
  int c = tid >> 2, g = tid & 3;
  const float2* r0 = (const float2*)(h1 + ((size_t)((b * 64 + c) * 224 + 2 * y)) * 224);
  const float2* r1 = r0 + 112;
  float sc = ss[2 * c], sh = ss[2 * c + 1];
  #pragma unroll
  for (int i = 0; i < 4; ++i) {
    int xl = g * 4 + i;
    float2 a = r0[x0 + xl], d = r1[x0 + xl];
    tile[xl][c] = (a.x + a.y + d.x + d.y) * 0.25f * sc + sh;
  }
  __syncthreads();
  int c2 = tid & 63, pg = tid >> 6;
  size_t obase = (size_t)b * HW2 + y * 112 + x0;
  #pragma unroll
  for (int i = 0; i < 4; ++i) {
    int xl = pg * 4 + i;
    out[(obase + xl) * 64 + c2] = tile[xl][c2];
  }
}

// ---------------- conv2: split-bf16 MFMA + fused BN2-stats, NHWC out ---------
// xin NHWC (4,HW2,64); wh/wl bf16 [128][576]; out NHWC fp32, +bias+relu
// part: [(o*784 + swz)*2 + {0,1}] per-block channel partial sum/sumsq
__global__ __launch_bounds__(256) void conv2_mfma3_kernel(
    const float* __restrict__ xin, const unsigned short* __restrict__ wh,
    const unsigned short* __restrict__ wl, const float* __restrict__ bias,
    float* __restrict__ out, float* __restrict__ part)
{
  __shared__ unsigned short wh_lds[128 * 32];
  __shared__ unsigned short wl_lds[128 * 32];
  __shared__ unsigned short xh_lds[64 * 32];
  __shared__ unsigned short xl_lds[64 * 32];
  __shared__ float bred[2][2][128];   // [px-half][sum/sq][o]
  int tid = threadIdx.x;
  // XCD-chunked swizzle: 784 blocks = 8 XCDs x 98
  int hw = blockIdx.y * 196 + blockIdx.x;
  int swz = (hw & 7) * 98 + (hw >> 3);
  int p0 = (swz % 196) * 64;
  int b  = swz / 196;
  const float* xb = xin + (size_t)b * HW2 * 64;

  f32x4 acc[4][2];
  #pragma unroll
  for (int f = 0; f < 4; ++f)
    #pragma unroll
    for (int g = 0; g < 2; ++g)
      acc[f][g] = (f32x4){0.f, 0.f, 0.f, 0.f};

  int wid = tid >> 6, l = tid & 63;
  int wo = (wid & 1) * 64, wp = (wid >> 1) * 32;
  int kgl = l >> 4, rl = l & 15;

  int pl = tid >> 2, kg = tid & 3;
  int pix = p0 + pl;
  int pi = pix / 112, pj = pix % 112;

  for (int step = 0; step < 18; ++step) {
    int k0 = step * 32;
    int kk = k0 >> 6;
    __syncthreads();
    #pragma unroll
    for (int it = 0; it < 2; ++it) {
      int task = tid + it * 256;
      int row = task >> 2, wkg = task & 3;
      size_t goff = (size_t)row * 576 + k0 + wkg * 8;
      int loff = row * 32 + ((wkg ^ ((row >> 1) & 3)) << 3);
      *(bf16x8*)(wh_lds + loff) = *(const bf16x8*)(wh + goff);
      *(bf16x8*)(wl_lds + loff) = *(const bf16x8*)(wl + goff);
    }
    {
      int dy = kk / 3 - 1, dx = kk % 3 - 1;
      int yy = pi + dy, xx = pj + dx;
      int c = (k0 & 63) + kg * 8;
      bf16x8 xvh, xvl;
      if (yy >= 0 && yy < 112 && xx >= 0 && xx < 112) {
        const float4* tp = (const float4*)(xb + ((size_t)(yy * 112 + xx)) * 64 + c);
        float4 t0 = tp[0], t1 = tp[1];
        float v[8] = {t0.x, t0.y, t0.z, t0.w, t1.x, t1.y, t1.z, t1.w};
        #pragma unroll
        for (int t = 0; t < 8; ++t) {
          unsigned short hsh = f2bf(v[t]);
          xvh[t] = (short)hsh;
          xvl[t] = (short)f2bf(v[t] - bf2f(hsh));
        }
      } else {
        #pragma unroll
        for (int t = 0; t < 8; ++t) { xvh[t] = 0; xvl[t] = 0; }
      }
      int loff = pl * 32 + ((kg ^ ((pl >> 1) & 3)) << 3);
      *(bf16x8*)(xh_lds + loff) = xvh;
      *(bf16x8*)(xl_lds + loff) = xvl;
    }
    __syncthreads();
    bf16x8 ah[4], al[4], bh[2], bl[2];
    #pragma unroll
    for (int f = 0; f < 4; ++f) {
      int r = wo + f * 16 + rl;
      int loff = r * 32 + ((kgl ^ ((r >> 1) & 3)) << 3);
      ah[f] = *(const bf16x8*)(wh_lds + loff);
      al[f] = *(const bf16x8*)(wl_lds + loff);
    }
    #pragma unroll
    for (int g = 0; g < 2; ++g) {
      int r = wp + g * 16 + rl;
      int loff = r * 32 + ((kgl ^ ((r >> 1) & 3)) << 3);
      bh[g] = *(const bf16x8*)(xh_lds + loff);
      bl[g] = *(const bf16x8*)(xl_lds + loff);
    }
    #pragma unroll
    for (int f = 0; f < 4; ++f)
      #pragma unroll
      for (int g = 0; g < 2; ++g) {
        acc[f][g] = __builtin_amdgcn_mfma_f32_16x16x32_bf16(ah[f], bh[g], acc[f][g], 0, 0, 0);
        acc[f][g] = __builtin_amdgcn_mfma_f32_16x16x32_bf16(ah[f], bl[g], acc[f][g], 0, 0, 0);
        acc[f][g] = __builtin_amdgcn_mfma_f32_16x16x32_bf16(al[f], bh[g], acc[f][g], 0, 0, 0);
      }
  }

  // epilogue: NHWC store + per-block channel partials (sum, sumsq)
  int jrow = (l >> 4) * 4, col = l & 15;
  float sv[4][4], sq[4][4];
  #pragma unroll
  for (int f = 0; f < 4; ++f)
    #pragma unroll
    for (int j = 0; j < 4; ++j) { sv[f][j] = 0.f; sq[f][j] = 0.f; }

  #pragma unroll
  for (int f = 0; f < 4; ++f) {
    int ob = wo + f * 16 + jrow;
    #pragma unroll
    for (int g = 0; g < 2; ++g) {
      int p = p0 + wp + g * 16 + col;
      float4 vv;
      float* pv = &vv.x;
      #pragma unroll
      for (int j = 0; j < 4; ++j) {
        float val = fmaxf(acc[f][g][j] + bias[ob + j], 0.f);
        pv[j] = val;
        sv[f][j] += val;
        sq[f][j] += val * val;
      }
      *(float4*)(out + ((size_t)b * HW2 + p) * 128 + ob) = vv;
    }
  }
  #pragma unroll
  for (int off = 1; off < 16; off <<= 1) {
    #pragma unroll
    for (int f = 0; f < 4; ++f)
      #pragma unroll
      for (int j = 0; j < 4; ++j) {
        sv[f][j] += __shfl_xor(sv[f][j], off, 64);
        sq[f][j] += __shfl_xor(sq[f][j], off, 64);
      }
  }
  if ((l & 15) == 0) {
    int ph = wid >> 1;
    #pragma unroll
    for (int f = 0; f < 4; ++f)
      #pragma unroll
      for (int j = 0; j < 4; ++j) {
        int o = wo + f * 16 + jrow + j;
        bred[ph][0][o] = sv[f][j];
        bred[ph][1][o] = sq[f][j];
      }
  }
  __syncthreads();
  if (tid < 128) {
    part[((size_t)tid * 784 + swz) * 2]     = bred[0][0][tid] + bred[1][0][tid];
    part[((size_t)tid * 784 + swz) * 2 + 1] = bred[0][1][tid] + bred[1][1][tid];
  }
}

// ---------------- BN2 apply (elementwise NHWC): fp32 out + bf16 out ----------
__global__ __launch_bounds__(256) void bn2_elem_kernel(
    const float* __restrict__ in, const float* __restrict__ ss,
    float* __restrict__ of32, unsigned short* __restrict__ obf)
{
  int idx = blockIdx.x * 256 + threadIdx.x;   // float4 index
  if (idx >= 4 * HW2 * 32) return;
  int c0 = (idx & 31) * 4;
  float4 v = ((const float4*)in)[idx];
  v.x = v.x * ss[2 * c0]     + ss[2 * c0 + 1];
  v.y = v.y * ss[2 * c0 + 2] + ss[2 * c0 + 3];
  v.z = v.z * ss[2 * c0 + 4] + ss[2 * c0 + 5];
  v.w = v.w * ss[2 * c0 + 6] + ss[2 * c0 + 7];
  ((float4*)of32)[idx] = v;
  bf16x4 bv;
  bv[0] = (short)f2bf(v.x); bv[1] = (short)f2bf(v.y);
  bv[2] = (short)f2bf(v.z); bv[3] = (short)f2bf(v.w);
  *(bf16x4*)(obf + (size_t)idx * 4) = bv;
}

// ---------------- offset conv: split-bf16 MFMA (M=32 padded, K=1152) --------
__global__ __launch_bounds__(256) void off_mfma3_kernel(
    const float* __restrict__ xin, const unsigned short* __restrict__ wh,
    const unsigned short* __restrict__ wl, const float* __restrict__ bias,
    float* __restrict__ out)
{
  __shared__ unsigned short wh_lds[32 * 32];
  __shared__ unsigned short wl_lds[32 * 32];
  __shared__ unsigned short xh_lds[128 * 32];
  __shared__ unsigned short xl_lds[128 * 32];
  int tid = threadIdx.x;
  // XCD-chunked swizzle: 392 blocks = 8 x 49
  int hw = blockIdx.y * 98 + blockIdx.x;
  int swz = (hw & 7) * 49 + (hw >> 3);
  int p0 = (swz % 98) * 128;
  int b  = swz / 98;
  const float* xb = xin + (size_t)b * HW2 * 128;

  f32x4 acc[2][2];
  #pragma unroll
  for (int f = 0; f < 2; ++f)
    #pragma unroll
    for (int g = 0; g < 2; ++g)
      acc[f][g] = (f32x4){0.f, 0.f, 0.f, 0.f};

  int wid = tid >> 6, l = tid & 63;
  int wp = wid * 32;
  int kgl = l >> 4, rl = l & 15;

  for (int step = 0; step < 36; ++step) {
    int k0 = step * 32;
    int kk = k0 >> 7;
    int dy = kk / 3 - 1, dx = kk % 3 - 1;
    __syncthreads();
    if (tid < 128) {
      int row = tid >> 2, wkg = tid & 3;
      size_t goff = (size_t)row * 1152 + k0 + wkg * 8;
      int loff = row * 32 + ((wkg ^ ((row >> 1) & 3)) << 3);
      *(bf16x8*)(wh_lds + loff) = *(const bf16x8*)(wh + goff);
      *(bf16x8*)(wl_lds + loff) = *(const bf16x8*)(wl + goff);
    }
    #pragma unroll
    for (int it = 0; it < 2; ++it) {
      int task = tid + it * 256;
      int pl = task >> 2, kg = task & 3;
      int pix = p0 + pl;
      int pi = pix / 112, pj = pix % 112;
      int yy = pi + dy, xx = pj + dx;
      int c = (k0 & 127) + kg * 8;
      bf16x8 xvh, xvl;
      if (yy >= 0 && yy < 112 && xx >= 0 && xx < 112) {
        const float4* tp = (const float4*)(xb + ((size_t)(yy * 112 + xx)) * 128 + c);
        float4 t0 = tp[0], t1 = tp[1];
        float v[8] = {t0.x, t0.y, t0.z, t0.w, t1.x, t1.y, t1.z, t1.w};
        #pragma unroll
        for (int t = 0; t < 8; ++t) {
          unsigned short hsh = f2bf(v[t]);
          xvh[t] = (short)hsh;
          xvl[t] = (short)f2bf(v[t] - bf2f(hsh));
        }
      } else {
        #pragma unroll
        for (int t = 0; t < 8; ++t) { xvh[t] = 0; xvl[t] = 0; }
      }
      int loff = pl * 32 + ((kg ^ ((pl >> 1) & 3)) << 3);
      *(bf16x8*)(xh_lds + loff) = xvh;
      *(bf16x8*)(xl_lds + loff) = xvl;
    }
    __syncthreads();
    bf16x8 ah[2], al[2], bh[2], bl[2];
    #pragma unroll
    for (int f = 0; f < 2; ++f) {
      int r = f * 16 + rl;
      int loff = r * 32 + ((kgl ^ ((r >> 1) & 3)) << 3);
      ah[f] = *(const bf16x8*)(wh_lds + loff);
      al[f] = *(const bf16x8*)(wl_lds + loff);
    }
    #pragma unroll
    for (int g = 0; g < 2; ++g) {
      int r = wp + g * 16 + rl;
      int loff = r * 32 + ((kgl ^ ((r >> 1) & 3)) << 3);
      bh[g] = *(const bf16x8*)(xh_lds + loff);
      bl[g] = *(const bf16x8*)(xl_lds + loff);
    }
    #pragma unroll
    for (int f = 0; f < 2; ++f)
      #pragma unroll
      for (int g = 0; g < 2; ++g) {
        acc[f][g] = __builtin_amdgcn_mfma_f32_16x16x32_bf16(ah[f], bh[g], acc[f][g], 0, 0, 0);
        acc[f][g] = __builtin_amdgcn_mfma_f32_16x16x32_bf16(ah[f], bl[g], acc[f][g], 0, 0, 0);
        acc[f][g] = __builtin_amdgcn_mfma_f32_16x16x32_bf16(al[f], bh[g], acc[f][g], 0, 0, 0);
      }
  }

  int jrow = (l >> 4) * 4, col = l & 15;
  #pragma unroll
  for (int f = 0; f < 2; ++f) {
    #pragma unroll
    for (int g = 0; g < 2; ++g) {
      int p = p0 + wp + g * 16 + col;
      #pragma unroll
      for (int j = 0; j < 4; ++j) {
        int o = f * 16 + jrow + j;
        if (o < 18)
          out[((size_t)(b * 18 + o)) * HW2 + p] = acc[f][g][j] + bias[o];
      }
    }
  }
}

// ---------------- fused deformable conv: bf16 gather + bf16 MFMA, BK=64 ------
// xin: BF16 NHWC (4,HW2,128); offs fp32; wb bf16 [128][1152]; out NCHW fp32
__global__ __launch_bounds__(256) void deform_mfma_kernel(
    const unsigned short* __restrict__ xin, const float* __restrict__ offs,
    const unsigned short* __restrict__ wb, float* __restrict__ out)
{
  __shared__ short          idx_s[576][4];
  __shared__ float          wt_s[576][4];
  __shared__ unsigned short w_lds[128 * 64];
  __shared__ unsigned short x_lds[64 * 64];

  int tid = threadIdx.x;
  // XCD-chunked swizzle: 784 blocks = 8 x 98
  int hw = blockIdx.y * 196 + blockIdx.x;
  int swz = (hw & 7) * 98 + (hw >> 3);
  int p0 = (swz % 196) * 64;
  int b  = swz / 196;
  const unsigned short* xb = xin + (size_t)b * HW2 * 128;

  for (int t = tid; t < 576; t += 256) {
    int p = t / 9, k = t % 9;
    int pix = p0 + p;
    int i = pix / 112, j = pix % 112;
    float offx = offs[((size_t)(b * 18 + k) * 112 + i) * 112 + j];
    float offy = offs[((size_t)(b * 18 + 9 + k) * 112 + i) * 112 + j];
    float px = (float)(i + k / 3) + offx;
    float py = (float)(j + k % 3) + offy;
    float fx = floorf(px), fy = floorf(py);
    float qltx = fminf(fmaxf(fx, 0.f), 113.f);
    float qlty = fminf(fmaxf(fy, 0.f), 113.f);
    float qrbx = fminf(fmaxf(fx + 1.f, 0.f), 113.f);
    float qrby = fminf(fmaxf(fy + 1.f, 0.f), 113.f);
    bool mx = (px < 1.f) || (px > 112.f);
    bool my = (py < 1.f) || (py > 112.f);
    float pxc = fminf(fmaxf(mx ? fx : px, 0.f), 113.f);
    float pyc = fminf(fmaxf(my ? fy : py, 0.f), 113.f);
    float glt = (1.f + (qltx - pxc)) * (1.f + (qlty - pyc));
    float grb = (1.f - (qrbx - pxc)) * (1.f - (qrby - pyc));
    float glb = (1.f + (qltx - pxc)) * (1.f - (qrby - pyc));
    float grt = (1.f - (qrbx - pxc)) * (1.f + (qlty - pyc));
    int ix0 = (int)qltx - 1, iy0 = (int)qlty - 1;
    int ix1 = (int)qrbx - 1, iy1 = (int)qrby - 1;
    bool vx0 = (ix0 >= 0 && ix0 < 112), vy0 = (iy0 >= 0 && iy0 < 112);
    bool vx1 = (ix1 >= 0 && ix1 < 112), vy1 = (iy1 >= 0 && iy1 < 112);
    idx_s[t][0] = (short)((vx0 && vy0) ? ix0 * 112 + iy0 : -1);  wt_s[t][0] = glt;
    idx_s[t][1] = (short)((vx1 && vy1) ? ix1 * 112 + iy1 : -1);  wt_s[t][1] = grb;
    idx_s[t][2] = (short)((vx0 && vy1) ? ix0 * 112 + iy1 : -1);  wt_s[t][2] = glb;
    idx_s[t][3] = (short)((vx1 && vy0) ? ix1 * 112 + iy0 : -1);  wt_s[t][3] = grt;
  }

  f32x4 acc[4][2];
  #pragma unroll
  for (int f = 0; f < 4; ++f)
    #pragma unroll
    for (int g = 0; g < 2; ++g)
      acc[f][g] = (f32x4){0.f, 0.f, 0.f, 0.f};

  int wid = tid >> 6;
  int l   = tid & 63;
  int wo = (wid & 1) * 64;
  int wp = (wid >> 1) * 32;
  int kgl = l >> 4;
  int rl  = l & 15;

  for (int step = 0; step < 18; ++step) {     // BK=64: one tap, 64 channels
    int k0 = step * 64;
    int kk = step >> 1;                        // tap 0..8 (2 steps per tap)
    int c0 = (step & 1) * 64;                  // channel base 0 or 64
    __syncthreads();

    // stage W tile: 128 rows x 64 k
    #pragma unroll
    for (int it = 0; it < 4; ++it) {
      int task = tid + it * 256;
      int row = task >> 3, kg8 = task & 7;
      int sub = kg8 >> 2, kg = kg8 & 3;
      bf16x8 wv = *(const bf16x8*)(wb + (size_t)row * 1152 + k0 + sub * 32 + kg * 8);
      *(bf16x8*)(w_lds + row * 64 + sub * 32 + ((kg ^ ((row >> 1) & 3)) << 3)) = wv;
    }

    // gather X (bf16 source): 64 px x 64 ch, shared idx/wt per (px,tap)
    {
      int pl = tid >> 2, kg = tid & 3;
      int c = c0 + kg * 8;
      int pk = pl * 9 + kk;
      float v0 = 0.f, v1 = 0.f, v2 = 0.f, v3 = 0.f;
      float v4 = 0.f, v5 = 0.f, v6 = 0.f, v7 = 0.f;
      float u0 = 0.f, u1 = 0.f, u2 = 0.f, u3 = 0.f;
      float u4 = 0.f, u5 = 0.f, u6 = 0.f, u7 = 0.f;
      #pragma unroll
      for (int q = 0; q < 4; ++q) {
        int s = idx_s[pk][q];
        if (s >= 0) {
          float wq = wt_s[pk][q];
          const bf16x8* tp = (const bf16x8*)(xb + (size_t)s * 128 + c);
          bf16x8 t0 = tp[0], t1 = tp[4];   // +32 ch = +4 bf16x8 units
          v0 += wq * bf2f((unsigned short)t0[0]); v1 += wq * bf2f((unsigned short)t0[1]);
          v2 += wq * bf2f((unsigned short)t0[2]); v3 += wq * bf2f((unsigned short)t0[3]);
          v4 += wq * bf2f((unsigned short)t0[4]); v5 += wq * bf2f((unsigned short)t0[5]);
          v6 += wq * bf2f((unsigned short)t0[6]); v7 += wq * bf2f((unsigned short)t0[7]);
          u0 += wq * bf2f((unsigned short)t1[0]); u1 += wq * bf2f((unsigned short)t1[1]);
          u2 += wq * bf2f((unsigned short)t1[2]); u3 += wq * bf2f((unsigned short)t1[3]);
          u4 += wq * bf2f((unsigned short)t1[4]); u5 += wq * bf2f((unsigned short)t1[5]);
          u6 += wq * bf2f((unsigned short)t1[6]); u7 += wq * bf2f((unsigned short)t1[7]);
        }
      }
      bf16x8 xv, xu;
      xv[0] = (short)f2bf(v0); xv[1] = (short)f2bf(v1);
      xv[2] = (short)f2bf(v2); xv[3] = (short)f2bf(v3);
      xv[4] = (short)f2bf(v4); xv[5] = (short)f2bf(v5);
      xv[6] = (short)f2bf(v6); xv[7] = (short)f2bf(v7);
      xu[0] = (short)f2bf(u0); xu[1] = (short)f2bf(u1);
      xu[2] = (short)f2bf(u2); xu[3] = (short)f2bf(u3);
      xu[4] = (short)f2bf(u4); xu[5] = (short)f2bf(u5);
      xu[6] = (short)f2bf(u6); xu[7] = (short)f2bf(u7);
      int sw = ((kg ^ ((pl >> 1) & 3)) << 3);
      *(bf16x8*)(x_lds + pl * 64 + sw) = xv;
      *(bf16x8*)(x_lds + pl * 64 + 32 + sw) = xu;
    }
    __syncthreads();

    #pragma unroll
    for (int sub = 0; sub < 2; ++sub) {
      bf16x8 af[4], bx[2];
      #pragma unroll
      for (int f = 0; f < 4; ++f) {
        int r = wo + f * 16 + rl;
        af[f] = *(const bf16x8*)(w_lds + r * 64 + sub * 32 + ((kgl ^ ((r >> 1) & 3)) << 3));
      }
      #pragma unroll
      for (int g = 0; g < 2; ++g) {
        int r = wp + g * 16 + rl;
        bx[g] = *(const bf16x8*)(x_lds + r * 64 + sub * 32 + ((kgl ^ ((r >> 1) & 3)) << 3));
      }
      #pragma unroll
      for (int f = 0; f < 4; ++f)
        #pragma unroll
        for (int g = 0; g < 2; ++g)
          acc[f][g] = __builtin_amdgcn_mfma_f32_16x16x32_bf16(af[f], bx[g], acc[f][g], 0, 0, 0);
    }
  }

  int jrow = (l >> 4) * 4;
  int col  = l & 15;
  #pragma unroll
  for (int f = 0; f < 4; ++f) {
    #pragma unroll
    for (int g = 0; g < 2; ++g) {
      #pragma unroll
      for (int j = 0; j < 4; ++j) {
        int o = wo + f * 16 + jrow + j;
        int p = p0 + wp + g * 16 + col;
        out[((size_t)(b * 128 + o)) * HW2 + p] = acc[f][g][j];
      }
    }
  }
}

extern "C" void kernel_launch(void* const* d_in, const int* in_sizes, int n_in,
                              void* d_out, int out_size, void* d_ws, size_t ws_size,
                              hipStream_t stream)
{
  const float* x       = (const float*)d_in[0];
  const float* conv1_w = (const float*)d_in[1];
  const float* conv1_b = (const float*)d_in[2];
  const float* bn1_g   = (const float*)d_in[3];
  const float* bn1_b   = (const float*)d_in[4];
  const float* conv2_w = (const float*)d_in[5];
  const float* conv2_b = (const float*)d_in[6];
  const float* bn2_g   = (const float*)d_in[7];
  const float* bn2_b   = (const float*)d_in[8];
  const float* off_w   = (const float*)d_in[9];
  const float* off_b   = (const float*)d_in[10];
  const float* conv4_w = (const float*)d_in[11];
  float* out = (float*)d_out;
  float* ws  = (float*)d_ws;

  // workspace (floats), aliased:
  // bufA 12,845,056: h1 (conv1 NCHW); after pool -> h3t NHWC fp32 = bufA[0:6.42M]
  // bufB 3,211,264: h2t NHWC(64) fp32; after conv2 -> h4b bf16 NHWC (6.42M shorts)
  // bufC 6,422,528: h4t NHWC(128) fp32
  // offs | part1 4096 | part2 200704 | ss 384 | bf16 weights
  float* bufA  = ws;
  float* bufB  = bufA + 12845056;
  float* bufC  = bufB + 3211264;
  float* offsb = bufC + 6422528;
  float* part1 = offsb + 903168;
  float* part2 = part1 + 4096;
  float* ss    = part2 + 200704;
  unsigned short* wbf  = (unsigned short*)(ss + 384);   // 147456
  unsigned short* wb2h = wbf + 147456;                  // 73728
  unsigned short* wb2l = wb2h + 73728;                  // 73728
  unsigned short* wboh = wb2l + 73728;                  // 36864
  unsigned short* wbol = wboh + 36864;                  // 36864

  float* h1  = bufA;
  float* h2t = bufB;
  float* h3t = bufA;                       // NHWC fp32 (conv2 out)
  float* h4t = bufC;                       // NHWC fp32 (BN2 out, for off conv)
  unsigned short* h4b = (unsigned short*)bufB;  // NHWC bf16 (BN2 out, for deform)

  prep_kernel<<<1008, 256, 0, stream>>>(conv4_w, conv2_w, off_w,
                                        wbf, wb2h, wb2l, wboh, wbol);

  conv1_tiled_kernel<<<dim3(196, 4), 256, 0, stream>>>(x, conv1_w, conv1_b, h1);
  bn_stats_part_kernel<<<dim3(32, 64), 256, 0, stream>>>(h1, part1, 64, HW1);
  bn_finalize_kernel<<<1, 128, 0, stream>>>(part1, 32, bn1_g, bn1_b, 1.f / (4.f * HW1), ss, 64);
  bn1_pool_nhwc_kernel<<<dim3(7, 112, 4), 256, 0, stream>>>(h1, ss, h2t);

  conv2_mfma3_kernel<<<dim3(196, 4), 256, 0, stream>>>(h2t, wb2h, wb2l, conv2_b, h3t, part2);
  bn_finalize_kernel<<<1, 128, 0, stream>>>(part2, 784, bn2_g, bn2_b, 1.f / (4.f * HW2), ss + 128, 128);
  bn2_elem_kernel<<<(4 * HW2 * 32 + 255) / 256, 256, 0, stream>>>(h3t, ss + 128, h4t, h4b);

  off_mfma3_kernel<<<dim3(98, 4), 256, 0, stream>>>(h4t, wboh, wbol, off_b, offsb);
  deform_mfma_kernel<<<dim3(196, 4), 256, 0, stream>>>(h4b, offsb, wbf, out);
}

// Round 11
// 300.784 us; speedup vs baseline: 1.2387x; 1.2387x over previous
//
#include <hip/hip_runtime.h>

#define HW1 50176   // 224*224
#define HW2 12544   // 112*112

typedef short bf16x8 __attribute__((ext_vector_type(8)));
typedef short bf16x4 __attribute__((ext_vector_type(4)));
typedef float f32x4  __attribute__((ext_vector_type(4)));

static __device__ __forceinline__ unsigned short f2bf(float f) {
  union { float f; unsigned int u; } v; v.f = f;
  unsigned int u = v.u;
  return (unsigned short)((u + 0x7fffu + ((u >> 16) & 1u)) >> 16);
}
static __device__ __forceinline__ float bf2f(unsigned short h) {
  union { unsigned int u; float f; } v; v.u = ((unsigned int)h) << 16;
  return v.f;
}

// ---------------- fused prep: 3 weight converts ------------------------------
__global__ __launch_bounds__(256) void prep_kernel(
    const float* __restrict__ conv4_w, const float* __restrict__ conv2_w,
    const float* __restrict__ off_w,
    unsigned short* __restrict__ wbf, unsigned short* __restrict__ wb2h,
    unsigned short* __restrict__ wb2l, unsigned short* __restrict__ wboh,
    unsigned short* __restrict__ wbol)
{
  int t = blockIdx.x * 256 + threadIdx.x;
  if (t < 147456) {                       // deform: [o][kk*128+c]
    int o = t / 1152, r = t % 1152;
    int kk = r / 128, c = r % 128;
    wbf[t] = f2bf(conv4_w[((size_t)o * 128 + c) * 9 + kk]);
  }
  int t2 = t - 147456;
  if (t2 >= 0 && t2 < 73728) {            // conv2 split: [o][kk*64+c]
    int o = t2 / 576, r = t2 % 576;
    int kk = r / 64, c = r % 64;
    float v = conv2_w[((size_t)o * 64 + c) * 9 + kk];
    unsigned short h = f2bf(v);
    wb2h[t2] = h; wb2l[t2] = f2bf(v - bf2f(h));
  }
  int t3 = t - (147456 + 73728);
  if (t3 >= 0 && t3 < 36864) {            // off conv split, padded to 32 rows
    int o = t3 / 1152, r = t3 % 1152;
    int kk = r / 128, c = r % 128;
    float v = (o < 18) ? off_w[((size_t)o * 128 + c) * 9 + kk] : 0.f;
    unsigned short h = f2bf(v);
    wboh[t3] = h; wbol[t3] = f2bf(v - bf2f(h));
  }
}

// ---------------- conv1: 3->64, 224x224, pad=1, +bias, relu, LDS-tiled ------
__global__ __launch_bounds__(256) void conv1_tiled_kernel(
    const float* __restrict__ x, const float* __restrict__ w,
    const float* __restrict__ bias, float* __restrict__ out)
{
  __shared__ float in_s[3][18][18];
  int tid = threadIdx.x;
  int tx = tid & 15, ty = tid >> 4;
  int tx0 = (blockIdx.x % 14) * 16, ty0 = (blockIdx.x / 14) * 16;
  int b = blockIdx.y;

  for (int t = tid; t < 972; t += 256) {
    int c = t / 324, r2 = t % 324;
    int r = r2 / 18, col = r2 % 18;
    int yy = ty0 + r - 1, xx = tx0 + col - 1;
    float v = 0.f;
    if (yy >= 0 && yy < 224 && xx >= 0 && xx < 224)
      v = x[((size_t)(b * 3 + c) * 224 + yy) * 224 + xx];
    in_s[c][r][col] = v;
  }
  __syncthreads();

  float xv[27];
  #pragma unroll
  for (int c = 0; c < 3; ++c)
    #pragma unroll
    for (int ky = 0; ky < 3; ++ky)
      #pragma unroll
      for (int kx = 0; kx < 3; ++kx)
        xv[c * 9 + ky * 3 + kx] = in_s[c][ty + ky][tx + kx];

  int oy = ty0 + ty, ox = tx0 + tx;
  size_t obase = ((size_t)b * 64) * HW1 + (size_t)oy * 224 + ox;
  for (int o0 = 0; o0 < 64; o0 += 16) {
    float acc[16];
    #pragma unroll
    for (int oi = 0; oi < 16; ++oi) acc[oi] = bias[o0 + oi];
    #pragma unroll
    for (int oi = 0; oi < 16; ++oi) {
      const float* wp = w + (size_t)(o0 + oi) * 27;
      #pragma unroll
      for (int k = 0; k < 27; ++k)
        acc[oi] += xv[k] * wp[k];
    }
    #pragma unroll
    for (int oi = 0; oi < 16; ++oi)
      out[obase + (size_t)(o0 + oi) * HW1] = fmaxf(acc[oi], 0.f);
  }
}

// ---------------- BN stats: per-block partials (DETERMINISTIC) ---------------
__global__ __launch_bounds__(256) void bn_stats_part_kernel(
    const float* __restrict__ in, float* __restrict__ part, int C, int HW)
{
  int c = blockIdx.y;
  int NB = gridDim.x;
  float s = 0.f, s2 = 0.f;
  int stride = NB * 256;
  int start = blockIdx.x * 256 + threadIdx.x;
  for (int b = 0; b < 4; ++b) {
    const float* p = in + (size_t)(b * C + c) * HW;
    for (int i = start; i < HW; i += stride) {
      float v = p[i];
      s += v; s2 += v * v;
    }
  }
  #pragma unroll
  for (int off = 32; off > 0; off >>= 1) {
    s  += __shfl_down(s, off, 64);
    s2 += __shfl_down(s2, off, 64);
  }
  __shared__ float red[8];
  int wid = threadIdx.x >> 6, lane = threadIdx.x & 63;
  if (lane == 0) { red[wid * 2] = s; red[wid * 2 + 1] = s2; }
  __syncthreads();
  if (threadIdx.x == 0) {
    float ts = 0.f, ts2 = 0.f;
    for (int i = 0; i < 4; ++i) { ts += red[i * 2]; ts2 += red[i * 2 + 1]; }
    part[((size_t)c * NB + blockIdx.x) * 2]     = ts;
    part[((size_t)c * NB + blockIdx.x) * 2 + 1] = ts2;
  }
}

// ---------------- BN finalize (small NB): fixed-order serial -----------------
__global__ void bn_finalize_kernel(const float* __restrict__ part, int NB,
                                   const float* __restrict__ g,
                                   const float* __restrict__ bb,
                                   float inv_n, float* __restrict__ ss, int C)
{
  int c = threadIdx.x;
  if (c < C) {
    float s = 0.f, s2 = 0.f;
    for (int i = 0; i < NB; ++i) {
      s  += part[((size_t)c * NB + i) * 2];
      s2 += part[((size_t)c * NB + i) * 2 + 1];
    }
    float m = s * inv_n;
    float v = s2 * inv_n - m * m;
    float sc = rsqrtf(v + 1e-5f) * g[c];
    ss[2 * c] = sc;
    ss[2 * c + 1] = bb[c] - m * sc;
  }
}

// ---------------- BN2 finalize (NB=784): parallel fixed-tree (deterministic) -
__global__ __launch_bounds__(256) void bn2_finalize_par_kernel(
    const float* __restrict__ part,   // [128][784][2]
    const float* __restrict__ g, const float* __restrict__ bb,
    float inv_n, float* __restrict__ ss)
{
  int c = blockIdx.x;       // one block per channel
  int tid = threadIdx.x;    // 256 threads
  const float* p = part + (size_t)c * 784 * 2;
  float s = 0.f, s2 = 0.f;
  // fixed per-thread index order: tid, tid+256, tid+512 (i < 784)
  for (int i = tid; i < 784; i += 256) {
    s  += p[i * 2];
    s2 += p[i * 2 + 1];
  }
  __shared__ float rs[256], rs2[256];
  rs[tid] = s; rs2[tid] = s2;
  __syncthreads();
  // fixed-shape tree: deterministic
  for (int off = 128; off > 0; off >>= 1) {
    if (tid < off) { rs[tid] += rs[tid + off]; rs2[tid] += rs2[tid + off]; }
    __syncthreads();
  }
  if (tid == 0) {
    float m = rs[0] * inv_n;
    float v = rs2[0] * inv_n - m * m;
    float sc = rsqrtf(v + 1e-5f) * g[c];
    ss[2 * c] = sc;
    ss[2 * c + 1] = bb[c] - m * sc;
  }
}

// ---------------- BN1 apply + 2x2 avgpool, NCHW -> NHWC (64 ch) -------------
__global__ __launch_bounds__(256) void bn1_pool_nhwc_kernel(
    const float* __restrict__ h1, const float* __restrict__ ss,
    float* __restrict__ out)
{
  __shared__ float tile[16][65];
  int b = blockIdx.z, y = blockIdx.y, x0 = blockIdx.x * 16;
  int tid = threadIdx.x;
  int c = tid >> 2, g = tid & 3;
  const float2* r0 = (const float2*)(h1 + ((size_t)((b * 64 + c) * 224 + 2 * y)) * 224);
  const float2* r1 = r0 + 112;
  float sc = ss[2 * c], sh = ss[2 * c + 1];
  #pragma unroll
  for (int i = 0; i < 4; ++i) {
    int xl = g * 4 + i;
    float2 a = r0[x0 + xl], d = r1[x0 + xl];
    tile[xl][c] = (a.x + a.y + d.x + d.y) * 0.25f * sc + sh;
  }
  __syncthreads();
  int c2 = tid & 63, pg = tid >> 6;
  size_t obase = (size_t)b * HW2 + y * 112 + x0;
  #pragma unroll
  for (int i = 0; i < 4; ++i) {
    int xl = pg * 4 + i;
    out[(obase + xl) * 64 + c2] = tile[xl][c2];
  }
}

// ---------------- conv2: split-bf16 MFMA + fused BN2-stats, NHWC out ---------
__global__ __launch_bounds__(256) void conv2_mfma3_kernel(
    const float* __restrict__ xin, const unsigned short* __restrict__ wh,
    const unsigned short* __restrict__ wl, const float* __restrict__ bias,
    float* __restrict__ out, float* __restrict__ part)
{
  __shared__ unsigned short wh_lds[128 * 32];
  __shared__ unsigned short wl_lds[128 * 32];
  __shared__ unsigned short xh_lds[64 * 32];
  __shared__ unsigned short xl_lds[64 * 32];
  __shared__ float bred[2][2][128];   // [px-half][sum/sq][o]
  int tid = threadIdx.x;
  // XCD-chunked swizzle: 784 blocks = 8 XCDs x 98
  int hw = blockIdx.y * 196 + blockIdx.x;
  int swz = (hw & 7) * 98 + (hw >> 3);
  int p0 = (swz % 196) * 64;
  int b  = swz / 196;
  const float* xb = xin + (size_t)b * HW2 * 64;

  f32x4 acc[4][2];
  #pragma unroll
  for (int f = 0; f < 4; ++f)
    #pragma unroll
    for (int g = 0; g < 2; ++g)
      acc[f][g] = (f32x4){0.f, 0.f, 0.f, 0.f};

  int wid = tid >> 6, l = tid & 63;
  int wo = (wid & 1) * 64, wp = (wid >> 1) * 32;
  int kgl = l >> 4, rl = l & 15;

  int pl = tid >> 2, kg = tid & 3;
  int pix = p0 + pl;
  int pi = pix / 112, pj = pix % 112;

  for (int step = 0; step < 18; ++step) {
    int k0 = step * 32;
    int kk = k0 >> 6;
    __syncthreads();
    #pragma unroll
    for (int it = 0; it < 2; ++it) {
      int task = tid + it * 256;
      int row = task >> 2, wkg = task & 3;
      size_t goff = (size_t)row * 576 + k0 + wkg * 8;
      int loff = row * 32 + ((wkg ^ ((row >> 1) & 3)) << 3);
      *(bf16x8*)(wh_lds + loff) = *(const bf16x8*)(wh + goff);
      *(bf16x8*)(wl_lds + loff) = *(const bf16x8*)(wl + goff);
    }
    {
      int dy = kk / 3 - 1, dx = kk % 3 - 1;
      int yy = pi + dy, xx = pj + dx;
      int c = (k0 & 63) + kg * 8;
      bf16x8 xvh, xvl;
      if (yy >= 0 && yy < 112 && xx >= 0 && xx < 112) {
        const float4* tp = (const float4*)(xb + ((size_t)(yy * 112 + xx)) * 64 + c);
        float4 t0 = tp[0], t1 = tp[1];
        float v[8] = {t0.x, t0.y, t0.z, t0.w, t1.x, t1.y, t1.z, t1.w};
        #pragma unroll
        for (int t = 0; t < 8; ++t) {
          unsigned short hsh = f2bf(v[t]);
          xvh[t] = (short)hsh;
          xvl[t] = (short)f2bf(v[t] - bf2f(hsh));
        }
      } else {
        #pragma unroll
        for (int t = 0; t < 8; ++t) { xvh[t] = 0; xvl[t] = 0; }
      }
      int loff = pl * 32 + ((kg ^ ((pl >> 1) & 3)) << 3);
      *(bf16x8*)(xh_lds + loff) = xvh;
      *(bf16x8*)(xl_lds + loff) = xvl;
    }
    __syncthreads();
    bf16x8 ah[4], al[4], bh[2], bl[2];
    #pragma unroll
    for (int f = 0; f < 4; ++f) {
      int r = wo + f * 16 + rl;
      int loff = r * 32 + ((kgl ^ ((r >> 1) & 3)) << 3);
      ah[f] = *(const bf16x8*)(wh_lds + loff);
      al[f] = *(const bf16x8*)(wl_lds + loff);
    }
    #pragma unroll
    for (int g = 0; g < 2; ++g) {
      int r = wp + g * 16 + rl;
      int loff = r * 32 + ((kgl ^ ((r >> 1) & 3)) << 3);
      bh[g] = *(const bf16x8*)(xh_lds + loff);
      bl[g] = *(const bf16x8*)(xl_lds + loff);
    }
    #pragma unroll
    for (int f = 0; f < 4; ++f)
      #pragma unroll
      for (int g = 0; g < 2; ++g) {
        acc[f][g] = __builtin_amdgcn_mfma_f32_16x16x32_bf16(ah[f], bh[g], acc[f][g], 0, 0, 0);
        acc[f][g] = __builtin_amdgcn_mfma_f32_16x16x32_bf16(ah[f], bl[g], acc[f][g], 0, 0, 0);
        acc[f][g] = __builtin_amdgcn_mfma_f32_16x16x32_bf16(al[f], bh[g], acc[f][g], 0, 0, 0);
      }
  }

  // epilogue: NHWC store + per-block channel partials (sum, sumsq)
  int jrow = (l >> 4) * 4, col = l & 15;
  float sv[4][4], sq[4][4];
  #pragma unroll
  for (int f = 0; f < 4; ++f)
    #pragma unroll
    for (int j = 0; j < 4; ++j) { sv[f][j] = 0.f; sq[f][j] = 0.f; }

  #pragma unroll
  for (int f = 0; f < 4; ++f) {
    int ob = wo + f * 16 + jrow;
    #pragma unroll
    for (int g = 0; g < 2; ++g) {
      int p = p0 + wp + g * 16 + col;
      float4 vv;
      float* pv = &vv.x;
      #pragma unroll
      for (int j = 0; j < 4; ++j) {
        float val = fmaxf(acc[f][g][j] + bias[ob + j], 0.f);
        pv[j] = val;
        sv[f][j] += val;
        sq[f][j] += val * val;
      }
      *(float4*)(out + ((size_t)b * HW2 + p) * 128 + ob) = vv;
    }
  }
  #pragma unroll
  for (int off = 1; off < 16; off <<= 1) {
    #pragma unroll
    for (int f = 0; f < 4; ++f)
      #pragma unroll
      for (int j = 0; j < 4; ++j) {
        sv[f][j] += __shfl_xor(sv[f][j], off, 64);
        sq[f][j] += __shfl_xor(sq[f][j], off, 64);
      }
  }
  if ((l & 15) == 0) {
    int ph = wid >> 1;
    #pragma unroll
    for (int f = 0; f < 4; ++f)
      #pragma unroll
      for (int j = 0; j < 4; ++j) {
        int o = wo + f * 16 + jrow + j;
        bred[ph][0][o] = sv[f][j];
        bred[ph][1][o] = sq[f][j];
      }
  }
  __syncthreads();
  if (tid < 128) {
    part[((size_t)tid * 784 + swz) * 2]     = bred[0][0][tid] + bred[1][0][tid];
    part[((size_t)tid * 784 + swz) * 2 + 1] = bred[0][1][tid] + bred[1][1][tid];
  }
}

// ---------------- BN2 apply (elementwise NHWC): fp32 out + bf16 out ----------
__global__ __launch_bounds__(256) void bn2_elem_kernel(
    const float* __restrict__ in, const float* __restrict__ ss,
    float* __restrict__ of32, unsigned short* __restrict__ obf)
{
  int idx = blockIdx.x * 256 + threadIdx.x;   // float4 index
  if (idx >= 4 * HW2 * 32) return;
  int c0 = (idx & 31) * 4;
  float4 v = ((const float4*)in)[idx];
  v.x = v.x * ss[2 * c0]     + ss[2 * c0 + 1];
  v.y = v.y * ss[2 * c0 + 2] + ss[2 * c0 + 3];
  v.z = v.z * ss[2 * c0 + 4] + ss[2 * c0 + 5];
  v.w = v.w * ss[2 * c0 + 6] + ss[2 * c0 + 7];
  ((float4*)of32)[idx] = v;
  bf16x4 bv;
  bv[0] = (short)f2bf(v.x); bv[1] = (short)f2bf(v.y);
  bv[2] = (short)f2bf(v.z); bv[3] = (short)f2bf(v.w);
  *(bf16x4*)(obf + (size_t)idx * 4) = bv;
}

// ---------------- offset conv: split-bf16 MFMA (M=32 padded, K=1152) --------
__global__ __launch_bounds__(256) void off_mfma3_kernel(
    const float* __restrict__ xin, const unsigned short* __restrict__ wh,
    const unsigned short* __restrict__ wl, const float* __restrict__ bias,
    float* __restrict__ out)
{
  __shared__ unsigned short wh_lds[32 * 32];
  __shared__ unsigned short wl_lds[32 * 32];
  __shared__ unsigned short xh_lds[128 * 32];
  __shared__ unsigned short xl_lds[128 * 32];
  int tid = threadIdx.x;
  // XCD-chunked swizzle: 392 blocks = 8 x 49
  int hw = blockIdx.y * 98 + blockIdx.x;
  int swz = (hw & 7) * 49 + (hw >> 3);
  int p0 = (swz % 98) * 128;
  int b  = swz / 98;
  const float* xb = xin + (size_t)b * HW2 * 128;

  f32x4 acc[2][2];
  #pragma unroll
  for (int f = 0; f < 2; ++f)
    #pragma unroll
    for (int g = 0; g < 2; ++g)
      acc[f][g] = (f32x4){0.f, 0.f, 0.f, 0.f};

  int wid = tid >> 6, l = tid & 63;
  int wp = wid * 32;
  int kgl = l >> 4, rl = l & 15;

  for (int step = 0; step < 36; ++step) {
    int k0 = step * 32;
    int kk = k0 >> 7;
    int dy = kk / 3 - 1, dx = kk % 3 - 1;
    __syncthreads();
    if (tid < 128) {
      int row = tid >> 2, wkg = tid & 3;
      size_t goff = (size_t)row * 1152 + k0 + wkg * 8;
      int loff = row * 32 + ((wkg ^ ((row >> 1) & 3)) << 3);
      *(bf16x8*)(wh_lds + loff) = *(const bf16x8*)(wh + goff);
      *(bf16x8*)(wl_lds + loff) = *(const bf16x8*)(wl + goff);
    }
    #pragma unroll
    for (int it = 0; it < 2; ++it) {
      int task = tid + it * 256;
      int pl = task >> 2, kg = task & 3;
      int pix = p0 + pl;
      int pi = pix / 112, pj = pix % 112;
      int yy = pi + dy, xx = pj + dx;
      int c = (k0 & 127) + kg * 8;
      bf16x8 xvh, xvl;
      if (yy >= 0 && yy < 112 && xx >= 0 && xx < 112) {
        const float4* tp = (const float4*)(xb + ((size_t)(yy * 112 + xx)) * 128 + c);
        float4 t0 = tp[0], t1 = tp[1];
        float v[8] = {t0.x, t0.y, t0.z, t0.w, t1.x, t1.y, t1.z, t1.w};
        #pragma unroll
        for (int t = 0; t < 8; ++t) {
          unsigned short hsh = f2bf(v[t]);
          xvh[t] = (short)hsh;
          xvl[t] = (short)f2bf(v[t] - bf2f(hsh));
        }
      } else {
        #pragma unroll
        for (int t = 0; t < 8; ++t) { xvh[t] = 0; xvl[t] = 0; }
      }
      int loff = pl * 32 + ((kg ^ ((pl >> 1) & 3)) << 3);
      *(bf16x8*)(xh_lds + loff) = xvh;
      *(bf16x8*)(xl_lds + loff) = xvl;
    }
    __syncthreads();
    bf16x8 ah[2], al[2], bh[2], bl[2];
    #pragma unroll
    for (int f = 0; f < 2; ++f) {
      int r = f * 16 + rl;
      int loff = r * 32 + ((kgl ^ ((r >> 1) & 3)) << 3);
      ah[f] = *(const bf16x8*)(wh_lds + loff);
      al[f] = *(const bf16x8*)(wl_lds + loff);
    }
    #pragma unroll
    for (int g = 0; g < 2; ++g) {
      int r = wp + g * 16 + rl;
      int loff = r * 32 + ((kgl ^ ((r >> 1) & 3)) << 3);
      bh[g] = *(const bf16x8*)(xh_lds + loff);
      bl[g] = *(const bf16x8*)(xl_lds + loff);
    }
    #pragma unroll
    for (int f = 0; f < 2; ++f)
      #pragma unroll
      for (int g = 0; g < 2; ++g) {
        acc[f][g] = __builtin_amdgcn_mfma_f32_16x16x32_bf16(ah[f], bh[g], acc[f][g], 0, 0, 0);
        acc[f][g] = __builtin_amdgcn_mfma_f32_16x16x32_bf16(ah[f], bl[g], acc[f][g], 0, 0, 0);
        acc[f][g] = __builtin_amdgcn_mfma_f32_16x16x32_bf16(al[f], bh[g], acc[f][g], 0, 0, 0);
      }
  }

  int jrow = (l >> 4) * 4, col = l & 15;
  #pragma unroll
  for (int f = 0; f < 2; ++f) {
    #pragma unroll
    for (int g = 0; g < 2; ++g) {
      int p = p0 + wp + g * 16 + col;
      #pragma unroll
      for (int j = 0; j < 4; ++j) {
        int o = f * 16 + jrow + j;
        if (o < 18)
          out[((size_t)(b * 18 + o)) * HW2 + p] = acc[f][g][j] + bias[o];
      }
    }
  }
}

// ---------------- fused deformable conv: bf16 gather + bf16 MFMA, BK=64 ------
__global__ __launch_bounds__(256) void deform_mfma_kernel(
    const unsigned short* __restrict__ xin, const float* __restrict__ offs,
    const unsigned short* __restrict__ wb, float* __restrict__ out)
{
  __shared__ short          idx_s[576][4];
  __shared__ float          wt_s[576][4];
  __shared__ unsigned short w_lds[128 * 64];
  __shared__ unsigned short x_lds[64 * 64];

  int tid = threadIdx.x;
  // XCD-chunked swizzle: 784 blocks = 8 x 98
  int hw = blockIdx.y * 196 + blockIdx.x;
  int swz = (hw & 7) * 98 + (hw >> 3);
  int p0 = (swz % 196) * 64;
  int b  = swz / 196;
  const unsigned short* xb = xin + (size_t)b * HW2 * 128;

  for (int t = tid; t < 576; t += 256) {
    int p = t / 9, k = t % 9;
    int pix = p0 + p;
    int i = pix / 112, j = pix % 112;
    float offx = offs[((size_t)(b * 18 + k) * 112 + i) * 112 + j];
    float offy = offs[((size_t)(b * 18 + 9 + k) * 112 + i) * 112 + j];
    float px = (float)(i + k / 3) + offx;
    float py = (float)(j + k % 3) + offy;
    float fx = floorf(px), fy = floorf(py);
    float qltx = fminf(fmaxf(fx, 0.f), 113.f);
    float qlty = fminf(fmaxf(fy, 0.f), 113.f);
    float qrbx = fminf(fmaxf(fx + 1.f, 0.f), 113.f);
    float qrby = fminf(fmaxf(fy + 1.f, 0.f), 113.f);
    bool mx = (px < 1.f) || (px > 112.f);
    bool my = (py < 1.f) || (py > 112.f);
    float pxc = fminf(fmaxf(mx ? fx : px, 0.f), 113.f);
    float pyc = fminf(fmaxf(my ? fy : py, 0.f), 113.f);
    float glt = (1.f + (qltx - pxc)) * (1.f + (qlty - pyc));
    float grb = (1.f - (qrbx - pxc)) * (1.f - (qrby - pyc));
    float glb = (1.f + (qltx - pxc)) * (1.f - (qrby - pyc));
    float grt = (1.f - (qrbx - pxc)) * (1.f + (qlty - pyc));
    int ix0 = (int)qltx - 1, iy0 = (int)qlty - 1;
    int ix1 = (int)qrbx - 1, iy1 = (int)qrby - 1;
    bool vx0 = (ix0 >= 0 && ix0 < 112), vy0 = (iy0 >= 0 && iy0 < 112);
    bool vx1 = (ix1 >= 0 && ix1 < 112), vy1 = (iy1 >= 0 && iy1 < 112);
    idx_s[t][0] = (short)((vx0 && vy0) ? ix0 * 112 + iy0 : -1);  wt_s[t][0] = glt;
    idx_s[t][1] = (short)((vx1 && vy1) ? ix1 * 112 + iy1 : -1);  wt_s[t][1] = grb;
    idx_s[t][2] = (short)((vx0 && vy1) ? ix0 * 112 + iy1 : -1);  wt_s[t][2] = glb;
    idx_s[t][3] = (short)((vx1 && vy0) ? ix1 * 112 + iy0 : -1);  wt_s[t][3] = grt;
  }

  f32x4 acc[4][2];
  #pragma unroll
  for (int f = 0; f < 4; ++f)
    #pragma unroll
    for (int g = 0; g < 2; ++g)
      acc[f][g] = (f32x4){0.f, 0.f, 0.f, 0.f};

  int wid = tid >> 6;
  int l   = tid & 63;
  int wo = (wid & 1) * 64;
  int wp = (wid >> 1) * 32;
  int kgl = l >> 4;
  int rl  = l & 15;

  for (int step = 0; step < 18; ++step) {     // BK=64: one tap, 64 channels
    int k0 = step * 64;
    int kk = step >> 1;                        // tap 0..8 (2 steps per tap)
    int c0 = (step & 1) * 64;                  // channel base 0 or 64
    __syncthreads();

    // stage W tile: 128 rows x 64 k
    #pragma unroll
    for (int it = 0; it < 4; ++it) {
      int task = tid + it * 256;
      int row = task >> 3, kg8 = task & 7;
      int sub = kg8 >> 2, kg = kg8 & 3;
      bf16x8 wv = *(const bf16x8*)(wb + (size_t)row * 1152 + k0 + sub * 32 + kg * 8);
      *(bf16x8*)(w_lds + row * 64 + sub * 32 + ((kg ^ ((row >> 1) & 3)) << 3)) = wv;
    }

    // gather X (bf16 source): 64 px x 64 ch, shared idx/wt per (px,tap)
    {
      int pl = tid >> 2, kg = tid & 3;
      int c = c0 + kg * 8;
      int pk = pl * 9 + kk;
      float v0 = 0.f, v1 = 0.f, v2 = 0.f, v3 = 0.f;
      float v4 = 0.f, v5 = 0.f, v6 = 0.f, v7 = 0.f;
      float u0 = 0.f, u1 = 0.f, u2 = 0.f, u3 = 0.f;
      float u4 = 0.f, u5 = 0.f, u6 = 0.f, u7 = 0.f;
      #pragma unroll
      for (int q = 0; q < 4; ++q) {
        int s = idx_s[pk][q];
        if (s >= 0) {
          float wq = wt_s[pk][q];
          const bf16x8* tp = (const bf16x8*)(xb + (size_t)s * 128 + c);
          bf16x8 t0 = tp[0], t1 = tp[4];   // +32 ch = +4 bf16x8 units
          v0 += wq * bf2f((unsigned short)t0[0]); v1 += wq * bf2f((unsigned short)t0[1]);
          v2 += wq * bf2f((unsigned short)t0[2]); v3 += wq * bf2f((unsigned short)t0[3]);
          v4 += wq * bf2f((unsigned short)t0[4]); v5 += wq * bf2f((unsigned short)t0[5]);
          v6 += wq * bf2f((unsigned short)t0[6]); v7 += wq * bf2f((unsigned short)t0[7]);
          u0 += wq * bf2f((unsigned short)t1[0]); u1 += wq * bf2f((unsigned short)t1[1]);
          u2 += wq * bf2f((unsigned short)t1[2]); u3 += wq * bf2f((unsigned short)t1[3]);
          u4 += wq * bf2f((unsigned short)t1[4]); u5 += wq * bf2f((unsigned short)t1[5]);
          u6 += wq * bf2f((unsigned short)t1[6]); u7 += wq * bf2f((unsigned short)t1[7]);
        }
      }
      bf16x8 xv, xu;
      xv[0] = (short)f2bf(v0); xv[1] = (short)f2bf(v1);
      xv[2] = (short)f2bf(v2); xv[3] = (short)f2bf(v3);
      xv[4] = (short)f2bf(v4); xv[5] = (short)f2bf(v5);
      xv[6] = (short)f2bf(v6); xv[7] = (short)f2bf(v7);
      xu[0] = (short)f2bf(u0); xu[1] = (short)f2bf(u1);
      xu[2] = (short)f2bf(u2); xu[3] = (short)f2bf(u3);
      xu[4] = (short)f2bf(u4); xu[5] = (short)f2bf(u5);
      xu[6] = (short)f2bf(u6); xu[7] = (short)f2bf(u7);
      int sw = ((kg ^ ((pl >> 1) & 3)) << 3);
      *(bf16x8*)(x_lds + pl * 64 + sw) = xv;
      *(bf16x8*)(x_lds + pl * 64 + 32 + sw) = xu;
    }
    __syncthreads();

    #pragma unroll
    for (int sub = 0; sub < 2; ++sub) {
      bf16x8 af[4], bx[2];
      #pragma unroll
      for (int f = 0; f < 4; ++f) {
        int r = wo + f * 16 + rl;
        af[f] = *(const bf16x8*)(w_lds + r * 64 + sub * 32 + ((kgl ^ ((r >> 1) & 3)) << 3));
      }
      #pragma unroll
      for (int g = 0; g < 2; ++g) {
        int r = wp + g * 16 + rl;
        bx[g] = *(const bf16x8*)(x_lds + r * 64 + sub * 32 + ((kgl ^ ((r >> 1) & 3)) << 3));
      }
      #pragma unroll
      for (int f = 0; f < 4; ++f)
        #pragma unroll
        for (int g = 0; g < 2; ++g)
          acc[f][g] = __builtin_amdgcn_mfma_f32_16x16x32_bf16(af[f], bx[g], acc[f][g], 0, 0, 0);
    }
  }

  int jrow = (l >> 4) * 4;
  int col  = l & 15;
  #pragma unroll
  for (int f = 0; f < 4; ++f) {
    #pragma unroll
    for (int g = 0; g < 2; ++g) {
      #pragma unroll
      for (int j = 0; j < 4; ++j) {
        int o = wo + f * 16 + jrow + j;
        int p = p0 + wp + g * 16 + col;
        out[((size_t)(b * 128 + o)) * HW2 + p] = acc[f][g][j];
      }
    }
  }
}

extern "C" void kernel_launch(void* const* d_in, const int* in_sizes, int n_in,
                              void* d_out, int out_size, void* d_ws, size_t ws_size,
                              hipStream_t stream)
{
  const float* x       = (const float*)d_in[0];
  const float* conv1_w = (const float*)d_in[1];
  const float* conv1_b = (const float*)d_in[2];
  const float* bn1_g   = (const float*)d_in[3];
  const float* bn1_b   = (const float*)d_in[4];
  const float* conv2_w = (const float*)d_in[5];
  const float* conv2_b = (const float*)d_in[6];
  const float* bn2_g   = (const float*)d_in[7];
  const float* bn2_b   = (const float*)d_in[8];
  const float* off_w   = (const float*)d_in[9];
  const float* off_b   = (const float*)d_in[10];
  const float* conv4_w = (const float*)d_in[11];
  float* out = (float*)d_out;
  float* ws  = (float*)d_ws;

  // workspace (floats), aliased:
  // bufA 12,845,056: h1 (conv1 NCHW); after pool -> h3t NHWC fp32 = bufA[0:6.42M]
  // bufB 3,211,264: h2t NHWC(64) fp32; after conv2 -> h4b bf16 NHWC (6.42M shorts)
  // bufC 6,422,528: h4t NHWC(128) fp32
  // offs | part1 4096 | part2 200704 | ss 384 | bf16 weights
  float* bufA  = ws;
  float* bufB  = bufA + 12845056;
  float* bufC  = bufB + 3211264;
  float* offsb = bufC + 6422528;
  float* part1 = offsb + 903168;
  float* part2 = part1 + 4096;
  float* ss    = part2 + 200704;
  unsigned short* wbf  = (unsigned short*)(ss + 384);   // 147456
  unsigned short* wb2h = wbf + 147456;                  // 73728
  unsigned short* wb2l = wb2h + 73728;                  // 73728
  unsigned short* wboh = wb2l + 73728;                  // 36864
  unsigned short* wbol = wboh + 36864;                  // 36864

  float* h1  = bufA;
  float* h2t = bufB;
  float* h3t = bufA;                       // NHWC fp32 (conv2 out)
  float* h4t = bufC;                       // NHWC fp32 (BN2 out, for off conv)
  unsigned short* h4b = (unsigned short*)bufB;  // NHWC bf16 (BN2 out, for deform)

  prep_kernel<<<1008, 256, 0, stream>>>(conv4_w, conv2_w, off_w,
                                        wbf, wb2h, wb2l, wboh, wbol);

  conv1_tiled_kernel<<<dim3(196, 4), 256, 0, stream>>>(x, conv1_w, conv1_b, h1);
  bn_stats_part_kernel<<<dim3(32, 64), 256, 0, stream>>>(h1, part1, 64, HW1);
  bn_finalize_kernel<<<1, 128, 0, stream>>>(part1, 32, bn1_g, bn1_b, 1.f / (4.f * HW1), ss, 64);
  bn1_pool_nhwc_kernel<<<dim3(7, 112, 4), 256, 0, stream>>>(h1, ss, h2t);

  conv2_mfma3_kernel<<<dim3(196, 4), 256, 0, stream>>>(h2t, wb2h, wb2l, conv2_b, h3t, part2);
  bn2_finalize_par_kernel<<<128, 256, 0, stream>>>(part2, bn2_g, bn2_b, 1.f / (4.f * HW2), ss + 128);
  bn2_elem_kernel<<<(4 * HW2 * 32 + 255) / 256, 256, 0, stream>>>(h3t, ss + 128, h4t, h4b);

  off_mfma3_kernel<<<dim3(98, 4), 256, 0, stream>>>(h4t, wboh, wbol, off_b, offsb);
  deform_mfma_kernel<<<dim3(196, 4), 256, 0, stream>>>(h4b, offsb, wbf, out);
}